// Round 1
// baseline (1445.960 us; speedup 1.0000x reference)
//
#include <hip/hip_runtime.h>
#include <hip/hip_bf16.h>
#include <math.h>

#define N_NODES 50000
#define N_EDGES 800000
#define NHEADS  4
#define NEG_SLOPE 0.2f

// ---------------------------------------------------------------------------
// fp32 tiled GEMM: C[M,N] = A[M,K] @ B[K,N].  BM=BN=64, BK=16, 256 thr, 4x4/thr
// ---------------------------------------------------------------------------
__global__ __launch_bounds__(256) void gemm_kernel(
    const float* __restrict__ A, const float* __restrict__ B,
    float* __restrict__ C, int M, int K, int N) {
  __shared__ float As[16][64];   // [k][m]
  __shared__ float Bs[16][64];   // [k][n]
  int tid = threadIdx.x;
  int tx = tid & 15, ty = tid >> 4;
  int bm = blockIdx.y * 64, bn = blockIdx.x * 64;
  int ar = tid >> 2, ak = (tid & 3) << 2;   // A: row ar (0..63), k-chunk ak
  int bkr = tid >> 4, bnc = (tid & 15) << 2; // B: k-row bkr (0..15), col bnc
  float acc[4][4] = {};
  int arow = bm + ar;
  for (int k0 = 0; k0 < K; k0 += 16) {
    float4 av = make_float4(0.f, 0.f, 0.f, 0.f);
    if (arow < M) av = *(const float4*)(A + (size_t)arow * K + k0 + ak);
    float4 bv = *(const float4*)(B + (size_t)(k0 + bkr) * N + bn + bnc);
    As[ak + 0][ar] = av.x; As[ak + 1][ar] = av.y;
    As[ak + 2][ar] = av.z; As[ak + 3][ar] = av.w;
    *(float4*)(&Bs[bkr][bnc]) = bv;
    __syncthreads();
#pragma unroll
    for (int k = 0; k < 16; ++k) {
      float4 a = *(const float4*)(&As[k][ty << 2]);
      float4 b = *(const float4*)(&Bs[k][tx << 2]);
      float aa[4] = {a.x, a.y, a.z, a.w};
      float bb[4] = {b.x, b.y, b.z, b.w};
#pragma unroll
      for (int i = 0; i < 4; ++i)
#pragma unroll
        for (int j = 0; j < 4; ++j) acc[i][j] += aa[i] * bb[j];
    }
    __syncthreads();
  }
  int col = bn + (tx << 2);
#pragma unroll
  for (int i = 0; i < 4; ++i) {
    int row = bm + (ty << 2) + i;
    if (row < M) {
      float4 o = make_float4(acc[i][0], acc[i][1], acc[i][2], acc[i][3]);
      *(float4*)(C + (size_t)row * N + col) = o;
    }
  }
}

// ---------------------------------------------------------------------------
// per-node attention scalars: a_s[n,h] = sum_c h[n,h,c]*asrc[h,c] (and adst)
// one wave per node, lanes = channels
// ---------------------------------------------------------------------------
template <int C>
__global__ void asad_kernel(const float* __restrict__ h,
                            const float* __restrict__ asrc,
                            const float* __restrict__ adst,
                            float* __restrict__ a_s, float* __restrict__ a_d,
                            int n) {
  int wid = threadIdx.x >> 6, l = threadIdx.x & 63;
  int node = blockIdx.x * 4 + wid;
  if (node >= n) return;
  const float* hp = h + (size_t)node * (NHEADS * C);
#pragma unroll
  for (int hd = 0; hd < NHEADS; ++hd) {
    float v = hp[hd * C + l];
    float ps = v * asrc[hd * C + l];
    float pd = v * adst[hd * C + l];
    if (C == 128) {
      float v2 = hp[hd * C + 64 + l];
      ps += v2 * asrc[hd * C + 64 + l];
      pd += v2 * adst[hd * C + 64 + l];
    }
#pragma unroll
    for (int o = 32; o >= 1; o >>= 1) {
      ps += __shfl_xor(ps, o);
      pd += __shfl_xor(pd, o);
    }
    if (l == 0) {
      a_s[node * NHEADS + hd] = ps;
      a_d[node * NHEADS + hd] = pd;
    }
  }
}

// ---------------------------------------------------------------------------
// edge_attr column sums (for mean)
// ---------------------------------------------------------------------------
__global__ void ea_colsum_kernel(const float* __restrict__ ea,
                                 float* __restrict__ sums, int E) {
  int tid = threadIdx.x;
  int col = tid & 15;
  float s = 0.f;
  for (int r = blockIdx.x * 16 + (tid >> 4); r < E; r += gridDim.x * 16)
    s += ea[(size_t)r * 16 + col];
  __shared__ float red[256];
  red[tid] = s;
  __syncthreads();
  for (int off = 128; off >= 16; off >>= 1) {
    if (tid < off) red[tid] += red[tid + off];
    __syncthreads();
  }
  if (tid < 16) atomicAdd(&sums[tid], red[tid]);
}

// ---------------------------------------------------------------------------
// wvec[l][k][h] = sum_c We_l[k, h*C+c] * ae_l[h,c];  ae_self[l][h] from mean ea
// single block
// ---------------------------------------------------------------------------
__global__ void wvec_kernel(const float* __restrict__ We0, const float* __restrict__ ae0,
                            const float* __restrict__ We1, const float* __restrict__ ae1,
                            const float* __restrict__ We2, const float* __restrict__ ae2,
                            const float* __restrict__ ea_sum,
                            float* __restrict__ wvec, float* __restrict__ ae_self) {
  __shared__ float sw[192];
  int tid = threadIdx.x;
  if (tid < 192) {
    int l = tid >> 6, rem = tid & 63, k = rem >> 2, hd = rem & 3;
    int C = (l == 2) ? 128 : 64;
    const float* We = (l == 0) ? We0 : (l == 1) ? We1 : We2;
    const float* ae = (l == 0) ? ae0 : (l == 1) ? ae1 : ae2;
    float s = 0.f;
    for (int c = 0; c < C; ++c) s += We[(size_t)k * (4 * C) + hd * C + c] * ae[hd * C + c];
    sw[tid] = s;
    wvec[tid] = s;  // layout: l*64 + k*4 + hd
  }
  __syncthreads();
  if (tid < 12) {
    int l = tid >> 2, hd = tid & 3;
    const float invE = 1.0f / (float)N_EDGES;
    float s = 0.f;
    for (int k = 0; k < 16; ++k) s += ea_sum[k] * invE * sw[l * 64 + k * 4 + hd];
    ae_self[tid] = s;
  }
}

// ---------------------------------------------------------------------------
// a_e[e][h] = sum_k ea[e,k] * wvec[k,h]
// ---------------------------------------------------------------------------
__global__ void ae_kernel(const float* __restrict__ ea, const float* __restrict__ wv,
                          float* __restrict__ a_e, int E) {
  int i = blockIdx.x * blockDim.x + threadIdx.x;
  int stride = gridDim.x * blockDim.x;
  for (int e = i; e < E; e += stride) {
    const float* row = ea + (size_t)e * 16;
    float s0 = 0, s1 = 0, s2 = 0, s3 = 0;
#pragma unroll
    for (int k = 0; k < 16; ++k) {
      float v = row[k];
      s0 += v * wv[k * 4 + 0];
      s1 += v * wv[k * 4 + 1];
      s2 += v * wv[k * 4 + 2];
      s3 += v * wv[k * 4 + 3];
    }
    *(float4*)(a_e + (size_t)e * 4) = make_float4(s0, s1, s2, s3);
  }
}

// ---------------------------------------------------------------------------
// CSR build
// ---------------------------------------------------------------------------
__global__ void deg_init_kernel(int* deg, int n) {
  int i = blockIdx.x * blockDim.x + threadIdx.x;
  if (i < n) deg[i] = 1;  // self-loop
}
__global__ void deg_count_kernel(const int* __restrict__ dst, int* deg, int E) {
  int i = blockIdx.x * blockDim.x + threadIdx.x;
  int s = gridDim.x * blockDim.x;
  for (; i < E; i += s) atomicAdd(&deg[dst[i]], 1);
}
__global__ void scan_kernel(const int* __restrict__ deg, int* __restrict__ offsets,
                            int* __restrict__ cursor, int n) {
  __shared__ int sums[1024];
  int tid = threadIdx.x;
  int chunk = (n + 1023) >> 10;
  int lo = tid * chunk; if (lo > n) lo = n;
  int hi = lo + chunk;  if (hi > n) hi = n;
  int s = 0;
  for (int i = lo; i < hi; ++i) s += deg[i];
  sums[tid] = s;
  __syncthreads();
  for (int d = 1; d < 1024; d <<= 1) {
    int v = (tid >= d) ? sums[tid - d] : 0;
    __syncthreads();
    sums[tid] += v;
    __syncthreads();
  }
  int run = (tid > 0) ? sums[tid - 1] : 0;
  for (int i = lo; i < hi; ++i) {
    offsets[i] = run;
    cursor[i] = run;
    run += deg[i];
  }
  if (tid == 0) offsets[n] = sums[1023];
}
__global__ void scatter_kernel(const int* __restrict__ src, const int* __restrict__ dst,
                               int* cursor, int* __restrict__ csr_src,
                               int* __restrict__ csr_eid, int E, int n) {
  int i = blockIdx.x * blockDim.x + threadIdx.x;
  int s = gridDim.x * blockDim.x;
  int tot = E + n;
  for (; i < tot; i += s) {
    int ss, dd, eid;
    if (i < E) { ss = src[i]; dd = dst[i]; eid = i; }
    else       { ss = i - E; dd = ss;     eid = E; }   // self-loop sentinel
    int pos = atomicAdd(&cursor[dd], 1);
    csr_src[pos] = ss;
    csr_eid[pos] = eid;
  }
}

// ---------------------------------------------------------------------------
// aggregation: per dst node softmax over incoming edges + weighted sum of h[src]
// block = 1 node, wave = 1 head, lanes = channels
// MODE 0: concat + bias + ELU (layers 0,1, C=64)
// MODE 1: head-mean + bias     (layer 2,  C=128)
// ---------------------------------------------------------------------------
template <int C, int MODE>
__global__ __launch_bounds__(256) void agg_kernel(
    const float* __restrict__ h, const float* __restrict__ a_s,
    const float* __restrict__ a_d, const float* __restrict__ a_e,
    const float* __restrict__ ae_self, const int* __restrict__ offsets,
    const int* __restrict__ csr_src, const int* __restrict__ csr_eid,
    const float* __restrict__ bias, float* __restrict__ y) {
  constexpr int HC = NHEADS * C;
  int node = blockIdx.x;
  int hd = threadIdx.x >> 6, l = threadIdx.x & 63;
  int beg = offsets[node], end = offsets[node + 1];
  float a_dn = a_d[node * NHEADS + hd];
  float aes = ae_self[hd];
  float acc0 = 0.f, acc1 = 0.f, denom = 0.f;

  if (end - beg <= 64) {
    int j = beg + l;
    bool valid = j < end;
    int s = 0;
    float al = -1e30f;
    if (valid) {
      s = csr_src[j];
      int eid = csr_eid[j];
      float aev = (eid < N_EDGES) ? a_e[(size_t)eid * NHEADS + hd] : aes;
      float v = a_s[s * NHEADS + hd] + a_dn + aev;
      al = (v > 0.f) ? v : NEG_SLOPE * v;
    }
    float m = al;
#pragma unroll
    for (int o = 32; o >= 1; o >>= 1) m = fmaxf(m, __shfl_xor(m, o));
    float ex = valid ? __expf(al - m) : 0.f;
    denom = ex;
#pragma unroll
    for (int o = 32; o >= 1; o >>= 1) denom += __shfl_xor(denom, o);
    int cnt = end - beg;
    for (int t = 0; t < cnt; ++t) {
      float w = __shfl(ex, t);
      int ss = __shfl(s, t);
      const float* hp = h + (size_t)ss * HC + hd * C;
      acc0 += w * hp[l];
      if (C == 128) acc1 += w * hp[64 + l];
    }
  } else {
    float m = -1e30f;
    for (int j0 = beg; j0 < end; j0 += 64) {
      int j = j0 + l;
      float al = -1e30f;
      if (j < end) {
        int s = csr_src[j];
        int eid = csr_eid[j];
        float aev = (eid < N_EDGES) ? a_e[(size_t)eid * NHEADS + hd] : aes;
        float v = a_s[s * NHEADS + hd] + a_dn + aev;
        al = (v > 0.f) ? v : NEG_SLOPE * v;
      }
      m = fmaxf(m, al);
    }
#pragma unroll
    for (int o = 32; o >= 1; o >>= 1) m = fmaxf(m, __shfl_xor(m, o));
    for (int j0 = beg; j0 < end; j0 += 64) {
      int j = j0 + l;
      int s = 0;
      float ex = 0.f;
      if (j < end) {
        s = csr_src[j];
        int eid = csr_eid[j];
        float aev = (eid < N_EDGES) ? a_e[(size_t)eid * NHEADS + hd] : aes;
        float v = a_s[s * NHEADS + hd] + a_dn + aev;
        float al = (v > 0.f) ? v : NEG_SLOPE * v;
        ex = __expf(al - m);
      }
      denom += ex;
      int cnt = min(64, end - j0);
      for (int t = 0; t < cnt; ++t) {
        float w = __shfl(ex, t);
        int ss = __shfl(s, t);
        const float* hp = h + (size_t)ss * HC + hd * C;
        acc0 += w * hp[l];
        if (C == 128) acc1 += w * hp[64 + l];
      }
    }
#pragma unroll
    for (int o = 32; o >= 1; o >>= 1) denom += __shfl_xor(denom, o);
  }

  float inv = 1.0f / (denom + 1e-16f);
  float v0 = acc0 * inv;
  if (MODE == 0) {
    float o = v0 + bias[hd * C + l];
    y[(size_t)node * HC + hd * C + l] = (o > 0.f) ? o : (__expf(o) - 1.f);
  } else {
    float v1 = acc1 * inv;
    __shared__ float red[NHEADS][128];
    red[hd][l] = v0;
    red[hd][64 + l] = v1;
    __syncthreads();
    if (hd == 0) {
#pragma unroll
      for (int q = 0; q < 2; ++q) {
        int c = l + q * 64;
        float sum = (red[0][c] + red[1][c] + red[2][c] + red[3][c]) * 0.25f + bias[c];
        y[(size_t)node * 128 + c] = sum;
      }
    }
  }
}

// ---------------------------------------------------------------------------
// global mean pool
// ---------------------------------------------------------------------------
__global__ void pool_kernel(const float* __restrict__ y, const int* __restrict__ batch,
                            float* __restrict__ pool, float* __restrict__ cnt, int n) {
  int n0 = blockIdx.x * 256;
  if (n0 >= n) return;
  int n1 = min(n0 + 256, n);
  int c = threadIdx.x;  // 128 threads
  float accum = 0.f;
  int cur = batch[n0];
  int cn = 0;
  for (int nd = n0; nd < n1; ++nd) {
    int g = batch[nd];
    if (g != cur) {
      atomicAdd(&pool[cur * 128 + c], accum);
      if (c == 0) atomicAdd(&cnt[cur], (float)cn);
      accum = 0.f; cn = 0; cur = g;
    }
    accum += y[(size_t)nd * 128 + c];
    cn++;
  }
  atomicAdd(&pool[cur * 128 + c], accum);
  if (c == 0) atomicAdd(&cnt[cur], (float)cn);
}
__global__ void finalize_kernel(const float* __restrict__ pool,
                                const float* __restrict__ cnt, float* __restrict__ out) {
  int i = blockIdx.x * blockDim.x + threadIdx.x;
  if (i < 64 * 128) out[i] = pool[i] / fmaxf(cnt[i >> 7], 1.f);
}

// ---------------------------------------------------------------------------
extern "C" void kernel_launch(void* const* d_in, const int* in_sizes, int n_in,
                              void* d_out, int out_size, void* d_ws, size_t ws_size,
                              hipStream_t stream) {
  const float* x = (const float*)d_in[0];
  const int* ei = (const int*)d_in[1];
  const float* ea = (const float*)d_in[2];
  const int* batch = (const int*)d_in[3];
  const float* W[3]    = {(const float*)d_in[4],  (const float*)d_in[10], (const float*)d_in[16]};
  const float* asrc[3] = {(const float*)d_in[5],  (const float*)d_in[11], (const float*)d_in[17]};
  const float* adst[3] = {(const float*)d_in[6],  (const float*)d_in[12], (const float*)d_in[18]};
  const float* Wep[3]  = {(const float*)d_in[7],  (const float*)d_in[13], (const float*)d_in[19]};
  const float* aep[3]  = {(const float*)d_in[8],  (const float*)d_in[14], (const float*)d_in[20]};
  const float* bp[3]   = {(const float*)d_in[9],  (const float*)d_in[15], (const float*)d_in[21]};

  char* ws = (char*)d_ws;
  size_t off = 0;
  auto take = [&](size_t bytes) -> void* {
    void* p = ws + off;
    off = (off + bytes + 255) & ~(size_t)255;
    return p;
  };
  float* zero_region = (float*)take((16 + 8192 + 64) * 4);
  float* ea_sum = zero_region;
  float* pool   = zero_region + 16;
  float* cnt    = zero_region + 16 + 8192;
  float* wvec    = (float*)take(192 * 4);
  float* ae_self = (float*)take(12 * 4);
  int* deg     = (int*)take((size_t)N_NODES * 4);
  int* offsets = (int*)take(((size_t)N_NODES + 1) * 4);
  int* cursor  = (int*)take((size_t)N_NODES * 4);
  int* csr_src = (int*)take((size_t)(N_EDGES + N_NODES) * 4);
  int* csr_eid = (int*)take((size_t)(N_EDGES + N_NODES) * 4);
  float* a_s  = (float*)take((size_t)N_NODES * NHEADS * 4);
  float* a_d  = (float*)take((size_t)N_NODES * NHEADS * 4);
  float* a_e  = (float*)take((size_t)N_EDGES * NHEADS * 4);
  float* hbuf = (float*)take((size_t)N_NODES * 512 * 4);
  float* ybuf = (float*)take((size_t)N_NODES * 256 * 4);

  const int* srcp = ei;
  const int* dstp = ei + N_EDGES;

  hipMemsetAsync(zero_region, 0, (16 + 8192 + 64) * 4, stream);
  ea_colsum_kernel<<<512, 256, 0, stream>>>(ea, ea_sum, N_EDGES);
  deg_init_kernel<<<(N_NODES + 255) / 256, 256, 0, stream>>>(deg, N_NODES);
  deg_count_kernel<<<2048, 256, 0, stream>>>(dstp, deg, N_EDGES);
  scan_kernel<<<1, 1024, 0, stream>>>(deg, offsets, cursor, N_NODES);
  scatter_kernel<<<2048, 256, 0, stream>>>(srcp, dstp, cursor, csr_src, csr_eid,
                                           N_EDGES, N_NODES);
  wvec_kernel<<<1, 256, 0, stream>>>(Wep[0], aep[0], Wep[1], aep[1], Wep[2], aep[2],
                                     ea_sum, wvec, ae_self);

  const float* cur_in = x;
  for (int l = 0; l < 3; ++l) {
    int K = (l == 0) ? 128 : 256;
    int C = (l == 2) ? 128 : 64;
    int HC = NHEADS * C;
    gemm_kernel<<<dim3(HC / 64, (N_NODES + 63) / 64), 256, 0, stream>>>(
        cur_in, W[l], hbuf, N_NODES, K, HC);
    if (C == 64)
      asad_kernel<64><<<(N_NODES + 3) / 4, 256, 0, stream>>>(hbuf, asrc[l], adst[l],
                                                             a_s, a_d, N_NODES);
    else
      asad_kernel<128><<<(N_NODES + 3) / 4, 256, 0, stream>>>(hbuf, asrc[l], adst[l],
                                                              a_s, a_d, N_NODES);
    ae_kernel<<<2048, 256, 0, stream>>>(ea, wvec + l * 64, a_e, N_EDGES);
    if (l < 2)
      agg_kernel<64, 0><<<N_NODES, 256, 0, stream>>>(hbuf, a_s, a_d, a_e,
                                                     ae_self + l * 4, offsets, csr_src,
                                                     csr_eid, bp[l], ybuf);
    else
      agg_kernel<128, 1><<<N_NODES, 256, 0, stream>>>(hbuf, a_s, a_d, a_e,
                                                      ae_self + l * 4, offsets, csr_src,
                                                      csr_eid, bp[l], ybuf);
    cur_in = ybuf;
  }
  pool_kernel<<<(N_NODES + 255) / 256, 128, 0, stream>>>(ybuf, batch, pool, cnt, N_NODES);
  finalize_kernel<<<(8192 + 255) / 256, 256, 0, stream>>>(pool, cnt, (float*)d_out);
}